// Round 6
// baseline (327.522 us; speedup 1.0000x reference)
//
#include <hip/hip_runtime.h>
#include <stdint.h>

typedef __attribute__((ext_vector_type(8))) short short8;
typedef __attribute__((ext_vector_type(4))) float floatx4;

// ---------- helpers ----------
__device__ __forceinline__ float bf16_to_f(uint16_t u) {
    union { uint32_t i; float f; } v; v.i = ((uint32_t)u) << 16; return v.f;
}
__device__ __forceinline__ uint16_t f_to_bf16(float f) {
    union { uint32_t i; float f; } v; v.f = f;
    uint32_t u = v.i;
    u += 0x7FFFu + ((u >> 16) & 1u);   // round-to-nearest-even
    return (uint16_t)(u >> 16);
}
__device__ __forceinline__ void gload16(const void* g, void* l) {
    __builtin_amdgcn_global_load_lds(
        (const __attribute__((address_space(1))) void*)g,
        (__attribute__((address_space(3))) void*)l, 16, 0, 0);
}
__device__ __forceinline__ float rcpf(float x) { return __builtin_amdgcn_rcpf(x); }

#define B_  32
#define T_  512
#define CF_ 2048
#define H_  128
#define G4_ 512   // 4*H
#define LOG2E 1.4426950408889634f

// =====================================================================
// k_cvt_all: all 6 weight tensors fp32 -> bf16 in ONE launch.
// =====================================================================
__global__ __launch_bounds__(256) void k_cvt_all(
        const float* __restrict__ Wfc, const float* __restrict__ Wih_f,
        const float* __restrict__ Wih_b, const float* __restrict__ Whh_f,
        const float* __restrict__ Whh_b, const float* __restrict__ Wout,
        uint16_t* __restrict__ WfcB, uint16_t* __restrict__ WihB,
        uint16_t* __restrict__ WhhB, uint16_t* __restrict__ WoutB) {
    const int blk = blockIdx.x;
    const float* s; uint16_t* d; int off;
    if (blk < 256)      { s = Wfc;   d = WfcB;          off = blk; }
    else if (blk < 320) { s = Wih_f; d = WihB;          off = blk - 256; }
    else if (blk < 384) { s = Wih_b; d = WihB + 65536;  off = blk - 320; }
    else if (blk < 448) { s = Whh_f; d = WhhB;          off = blk - 384; }
    else if (blk < 512) { s = Whh_b; d = WhhB + 65536;  off = blk - 448; }
    else                { s = Wout;  d = WoutB;         off = blk - 512; }
    const int i = off * 1024 + threadIdx.x * 4;
    float4 v = *(const float4*)&s[i];
    ushort4 o;
    o.x = f_to_bf16(v.x); o.y = f_to_bf16(v.y);
    o.z = f_to_bf16(v.z); o.w = f_to_bf16(v.w);
    *(ushort4*)&d[i] = o;
}

// =====================================================================
// k_fc1p: fc1 partial GEMM with K-SPLIT (ks = blockIdx.z, K-slice 512).
// Grid (16 t, 32 b, 4 ks) = 2048 WGs -> 4 WG/CU (32 waves, full cap):
// cross-WG overlap hides the per-iter barrier drains that killed the
// 1-2 WG/CU variants. Per WG: 8 iters of BK=64, fp32 partial to P
// (no bias). Wave w owns d-rows [16w,16w+16).
// =====================================================================
__global__ __launch_bounds__(512) void k_fc1p(const float* __restrict__ x,
                                              const uint16_t* __restrict__ WfcB,
                                              float* __restrict__ P) {
    __shared__ float tile[32 * 65];                    // [t][cf] fp32
    __shared__ __align__(16) uint16_t As[8192];        // W chunk-major (8c x 128r x 8)
    __shared__ __align__(16) uint16_t Bs[2176];        // xT chunk-major (8c x 34 x 8)

    const int bb = blockIdx.y, n0 = blockIdx.x * 32;
    const int k_base = blockIdx.z * 512;
    const int tid = threadIdx.x, w = tid >> 6, l = tid & 63;
    const int lm = l & 15, lk = l >> 4;
    const float* xb = x + (size_t)bb * CF_ * T_;

    const int t4 = (tid & 7) * 4, cf_r = tid >> 3;     // stage-1 map
    const int kk = (tid & 15) * 4, t_r = tid >> 4;     // stage-2 map

    float4 xv = *(const float4*)&xb[(size_t)(k_base + cf_r) * T_ + n0 + t4];

    const int dw = w * 16;
    floatx4 acc[2] = {};
    for (int k0 = 0; k0 < 512; k0 += 64) {
        __syncthreads();
        tile[(t4 + 0) * 65 + cf_r] = xv.x;
        tile[(t4 + 1) * 65 + cf_r] = xv.y;
        tile[(t4 + 2) * 65 + cf_r] = xv.z;
        tile[(t4 + 3) * 65 + cf_r] = xv.w;
        gload16(WfcB + (size_t)l * CF_ + k_base + k0 + w * 8,        As + (w * 128 + l) * 8);
        gload16(WfcB + (size_t)(64 + l) * CF_ + k_base + k0 + w * 8, As + (w * 128 + 64 + l) * 8);
        __syncthreads();
        if (k0 + 64 < 512)
            xv = *(const float4*)&xb[(size_t)(k_base + k0 + 64 + cf_r) * T_ + n0 + t4];
        {
            ushort4 o;
            o.x = f_to_bf16(tile[t_r * 65 + kk + 0]);
            o.y = f_to_bf16(tile[t_r * 65 + kk + 1]);
            o.z = f_to_bf16(tile[t_r * 65 + kk + 2]);
            o.w = f_to_bf16(tile[t_r * 65 + kk + 3]);
            *(ushort4*)&Bs[((kk >> 3) * 34 + t_r) * 8 + (kk & 7)] = o;
        }
        __syncthreads();
        short8 a[2], bfr[2][2];
        #pragma unroll
        for (int kf = 0; kf < 2; ++kf) {
            a[kf] = *(const short8*)&As[((kf * 4 + lk) * 128 + dw + lm) * 8];
            #pragma unroll
            for (int nf = 0; nf < 2; ++nf)
                bfr[nf][kf] = *(const short8*)&Bs[((kf * 4 + lk) * 34 + nf * 16 + lm) * 8];
        }
        #pragma unroll
        for (int nf = 0; nf < 2; ++nf) {
            acc[nf] = __builtin_amdgcn_mfma_f32_16x16x32_bf16(a[0], bfr[nf][0], acc[nf], 0, 0, 0);
            acc[nf] = __builtin_amdgcn_mfma_f32_16x16x32_bf16(a[1], bfr[nf][1], acc[nf], 0, 0, 0);
        }
    }
    // epilogue: fp32 partial, P[ks][b][t][d]
    const int d0 = dw + lk * 4;
    #pragma unroll
    for (int nf = 0; nf < 2; ++nf) {
        const int t = n0 + nf * 16 + lm;
        float4 o = {acc[nf][0], acc[nf][1], acc[nf][2], acc[nf][3]};
        *(float4*)&P[((size_t)(blockIdx.z * B_ + bb) * T_ + t) * H_ + d0] = o;
    }
}

// =====================================================================
// k_fc1r: reduce 4 K-split partials + bias -> bf16 Hfc tile in LDS,
// then input-projection (phase B): Xp[dir][t][g] = Wih_dir @ Hfc^T + b.
// Grid (16 t, 32 b) = 512 WGs, 512 thr = 8 waves.
// Wave w: dir=w>>2, g-slab (w&3)*64 (+256 per it).
// =====================================================================
__global__ __launch_bounds__(512) void k_fc1r(const float* __restrict__ P,
                                              const float* __restrict__ bfc,
                                              const uint16_t* __restrict__ WihB,
                                              const float* __restrict__ b_f,
                                              const float* __restrict__ b_b,
                                              uint16_t* __restrict__ Xp) {
    __shared__ __align__(16) uint16_t Hs2[4352];       // Hfc chunk-major (16c x 34 x 8)
    const int bb = blockIdx.y, n0 = blockIdx.x * 32;
    const int tid = threadIdx.x, w = tid >> 6, l = tid & 63;
    const int lm = l & 15, lk = l >> 4;

    // ---- reduce + bias + cvt ----
    {
        const int t = tid >> 4, d8 = (tid & 15) * 8;
        float4 s0 = {0.f, 0.f, 0.f, 0.f}, s1 = {0.f, 0.f, 0.f, 0.f};
        #pragma unroll
        for (int ks = 0; ks < 4; ++ks) {
            const float* p = &P[((size_t)(ks * B_ + bb) * T_ + n0 + t) * H_ + d8];
            float4 a = *(const float4*)p;
            float4 b = *(const float4*)(p + 4);
            s0.x += a.x; s0.y += a.y; s0.z += a.z; s0.w += a.w;
            s1.x += b.x; s1.y += b.y; s1.z += b.z; s1.w += b.w;
        }
        const float4 bv0 = *(const float4*)&bfc[d8];
        const float4 bv1 = *(const float4*)&bfc[d8 + 4];
        ushort4 o0, o1;
        o0.x = f_to_bf16(s0.x + bv0.x); o0.y = f_to_bf16(s0.y + bv0.y);
        o0.z = f_to_bf16(s0.z + bv0.z); o0.w = f_to_bf16(s0.w + bv0.w);
        o1.x = f_to_bf16(s1.x + bv1.x); o1.y = f_to_bf16(s1.y + bv1.y);
        o1.z = f_to_bf16(s1.z + bv1.z); o1.w = f_to_bf16(s1.w + bv1.w);
        *(ushort4*)&Hs2[((d8 >> 3) * 34 + t) * 8] = o0;
        *(ushort4*)&Hs2[((d8 >> 3) * 34 + t) * 8 + 4] = o1;
    }
    __syncthreads();

    // ---- phase B ----
    const int dirw = w >> 2;
    const int db   = dirw * B_ + bb;
    const uint16_t* Wp = WihB + (size_t)dirw * (G4_ * H_);
    const float* bi = dirw ? b_b : b_f;
    #pragma unroll
    for (int it = 0; it < 2; ++it) {
        const int gbase = (w & 3) * 64 + it * 256;
        short8 aw[4][4];
        #pragma unroll
        for (int mf = 0; mf < 4; ++mf)
            #pragma unroll
            for (int kf = 0; kf < 4; ++kf)
                aw[mf][kf] = *(const short8*)&Wp[(size_t)(gbase + mf * 16 + lm) * H_ + kf * 32 + lk * 8];
        short8 bbf[4];
        floatx4 acc2[4][2] = {};
        #pragma unroll
        for (int nf = 0; nf < 2; ++nf) {
            #pragma unroll
            for (int kf = 0; kf < 4; ++kf)
                bbf[kf] = *(const short8*)&Hs2[((kf * 4 + lk) * 34 + nf * 16 + lm) * 8];
            #pragma unroll
            for (int mf = 0; mf < 4; ++mf)
                #pragma unroll
                for (int kf = 0; kf < 4; ++kf)
                    acc2[mf][nf] = __builtin_amdgcn_mfma_f32_16x16x32_bf16(aw[mf][kf], bbf[kf], acc2[mf][nf], 0, 0, 0);
        }
        #pragma unroll
        for (int mf = 0; mf < 4; ++mf) {
            const int g0 = gbase + mf * 16 + lk * 4;
            const float4 bv = *(const float4*)&bi[g0];
            #pragma unroll
            for (int nf = 0; nf < 2; ++nf) {
                const int t = n0 + nf * 16 + lm;
                ushort4 o;
                o.x = f_to_bf16(acc2[mf][nf][0] + bv.x);
                o.y = f_to_bf16(acc2[mf][nf][1] + bv.y);
                o.z = f_to_bf16(acc2[mf][nf][2] + bv.z);
                o.w = f_to_bf16(acc2[mf][nf][3] + bv.w);
                *(ushort4*)&Xp[((size_t)db * T_ + t) * G4_ + g0] = o;
            }
        }
    }
}

// =====================================================================
// k_lstm: MFMA recurrence (unchanged).
// =====================================================================
__global__ __launch_bounds__(512) void k_lstm(const uint16_t* __restrict__ Xp,
                                              const uint16_t* __restrict__ WhhB,
                                              uint16_t* __restrict__ hs) {
    __shared__ __align__(16) uint16_t h_sh[16 * 136];
    __shared__ float z_sh[16 * 516];
    const int dir = blockIdx.y, t0 = blockIdx.x * 16;
    const int tid = threadIdx.x, w = tid >> 6, l = tid & 63;
    const int lm = l & 15, lk = l >> 4;
    const int gw = w * 64;
    const uint16_t* Wp = WhhB + dir * (G4_ * H_);

    short8 bw[4][4];
    #pragma unroll
    for (int nf = 0; nf < 4; ++nf)
        #pragma unroll
        for (int kf = 0; kf < 4; ++kf)
            bw[nf][kf] = *(const short8*)&Wp[(size_t)(gw + nf * 16 + lm) * H_ + kf * 32 + lk * 8];

    for (int i = tid; i < 16 * 136; i += 512) h_sh[i] = 0;
    const int hh = tid & 127, tq = tid >> 7;
    float c[4] = {0.f, 0.f, 0.f, 0.f};
    __syncthreads();

    for (int s = 0; s < 32; ++s) {
        const int b_idx = dir ? (31 - s) : s;
        const uint16_t* xp = Xp + ((size_t)(dir * B_ + b_idx) * T_ + t0) * G4_;
        uint16_t xv[4][4];
        #pragma unroll
        for (int j = 0; j < 4; ++j)
            #pragma unroll
            for (int gg = 0; gg < 4; ++gg)
                xv[j][gg] = xp[(size_t)(tq * 4 + j) * G4_ + gg * H_ + hh];

        short8 af[4];
        #pragma unroll
        for (int kf = 0; kf < 4; ++kf)
            af[kf] = *(const short8*)&h_sh[lm * 136 + kf * 32 + lk * 8];
        floatx4 acc[4] = {};
        #pragma unroll
        for (int nf = 0; nf < 4; ++nf)
            #pragma unroll
            for (int kf = 0; kf < 4; ++kf)
                acc[nf] = __builtin_amdgcn_mfma_f32_16x16x32_bf16(af[kf], bw[nf][kf], acc[nf], 0, 0, 0);
        #pragma unroll
        for (int nf = 0; nf < 4; ++nf)
            #pragma unroll
            for (int r = 0; r < 4; ++r)
                z_sh[(lk * 4 + r) * 516 + gw + nf * 16 + lm] = acc[nf][r];
        __syncthreads();

        #pragma unroll
        for (int j = 0; j < 4; ++j) {
            const int t = tq * 4 + j;
            const float* zr = &z_sh[t * 516];
            float zi = zr[hh]            + bf16_to_f(xv[j][0]);
            float zf = zr[H_ + hh]       + bf16_to_f(xv[j][1]);
            float zg = zr[2 * H_ + hh]   + bf16_to_f(xv[j][2]);
            float zo = zr[3 * H_ + hh]   + bf16_to_f(xv[j][3]);
            float si = rcpf(1.f + __builtin_amdgcn_exp2f(-LOG2E * zi));
            float sf = rcpf(1.f + __builtin_amdgcn_exp2f(-LOG2E * zf));
            float so = rcpf(1.f + __builtin_amdgcn_exp2f(-LOG2E * zo));
            float tg = 1.f - 2.f * rcpf(1.f + __builtin_amdgcn_exp2f(2.f * LOG2E * zg));
            c[j] = sf * c[j] + si * tg;
            float tc = 1.f - 2.f * rcpf(1.f + __builtin_amdgcn_exp2f(2.f * LOG2E * c[j]));
            float hn = so * tc;
            uint16_t hb = f_to_bf16(hn);
            h_sh[t * 136 + hh] = hb;
            hs[((size_t)b_idx * T_ + t0 + t) * 256 + dir * H_ + hh] = hb;
        }
        __syncthreads();
    }
}

// =====================================================================
// k_outm: out[b][e][t] fp32 = W_out(128x256) @ hs[b]^T + b_out
// 64x64 tiles, BK=64, grid (8, 2, 32)
// =====================================================================
__global__ __launch_bounds__(256) void k_outm(const uint16_t* __restrict__ WoutB,
                                              const uint16_t* __restrict__ hs,
                                              const float* __restrict__ bout,
                                              float* __restrict__ out) {
    __shared__ __align__(16) uint16_t As[4096], Bs[4096];
    const int b = blockIdx.z, m0 = blockIdx.y * 64, n0 = blockIdx.x * 64;
    const int tid = threadIdx.x, w = tid >> 6, l = tid & 63;
    const int wm = (w >> 1) * 32, wn = (w & 1) * 32;
    const int lm = l & 15, lk = l >> 4;
    const uint16_t* gA = WoutB + (size_t)(m0 + l) * 256;
    const uint16_t* gB = hs + ((size_t)b * T_ + n0 + l) * 256;
    floatx4 acc[2][2] = {};
    for (int k0 = 0; k0 < 256; k0 += 64) {
        __syncthreads();
        gload16(gA + k0 + (2 * w) * 8,     As + ((2 * w) * 64 + l) * 8);
        gload16(gA + k0 + (2 * w + 1) * 8, As + ((2 * w + 1) * 64 + l) * 8);
        gload16(gB + k0 + (2 * w) * 8,     Bs + ((2 * w) * 64 + l) * 8);
        gload16(gB + k0 + (2 * w + 1) * 8, Bs + ((2 * w + 1) * 64 + l) * 8);
        __syncthreads();
        short8 a[2][2], bfr[2][2];
        #pragma unroll
        for (int kf = 0; kf < 2; ++kf) {
            #pragma unroll
            for (int mf = 0; mf < 2; ++mf)
                a[mf][kf] = *(const short8*)&As[((kf * 4 + lk) * 64 + wm + mf * 16 + lm) * 8];
            #pragma unroll
            for (int nf = 0; nf < 2; ++nf)
                bfr[nf][kf] = *(const short8*)&Bs[((kf * 4 + lk) * 64 + wn + nf * 16 + lm) * 8];
        }
        #pragma unroll
        for (int mf = 0; mf < 2; ++mf)
            #pragma unroll
            for (int nf = 0; nf < 2; ++nf) {
                acc[mf][nf] = __builtin_amdgcn_mfma_f32_16x16x32_bf16(a[mf][0], bfr[nf][0], acc[mf][nf], 0, 0, 0);
                acc[mf][nf] = __builtin_amdgcn_mfma_f32_16x16x32_bf16(a[mf][1], bfr[nf][1], acc[mf][nf], 0, 0, 0);
            }
    }
    #pragma unroll
    for (int mf = 0; mf < 2; ++mf) {
        const int e0 = m0 + wm + mf * 16 + lk * 4;
        const float4 bv = *(const float4*)&bout[e0];
        #pragma unroll
        for (int nf = 0; nf < 2; ++nf) {
            const int t = n0 + wn + nf * 16 + lm;
            out[((size_t)b * H_ + e0 + 0) * T_ + t] = acc[mf][nf][0] + bv.x;
            out[((size_t)b * H_ + e0 + 1) * T_ + t] = acc[mf][nf][1] + bv.y;
            out[((size_t)b * H_ + e0 + 2) * T_ + t] = acc[mf][nf][2] + bv.z;
            out[((size_t)b * H_ + e0 + 3) * T_ + t] = acc[mf][nf][3] + bv.w;
        }
    }
}

// =====================================================================
extern "C" void kernel_launch(void* const* d_in, const int* in_sizes, int n_in,
                              void* d_out, int out_size, void* d_ws, size_t ws_size,
                              hipStream_t stream) {
    const float* x     = (const float*)d_in[0];
    const float* Wfc   = (const float*)d_in[1];
    const float* bfc   = (const float*)d_in[2];
    const float* Wih_f = (const float*)d_in[3];
    const float* Whh_f = (const float*)d_in[4];
    const float* b_f   = (const float*)d_in[5];
    const float* Wih_b = (const float*)d_in[6];
    const float* Whh_b = (const float*)d_in[7];
    const float* b_b   = (const float*)d_in[8];
    const float* Wout  = (const float*)d_in[9];
    const float* bout  = (const float*)d_in[10];
    float* out = (float*)d_out;

    char* ws = (char*)d_ws;
    uint16_t* Xp    = (uint16_t*)(ws);                 // 33,554,432 B
    uint16_t* hsB   = (uint16_t*)(ws + 33554432);      //  8,388,608 B
    uint16_t* WfcB  = (uint16_t*)(ws + 41943040);      //    524,288 B
    uint16_t* WihB  = (uint16_t*)(ws + 42467328);      //    262,144 B
    uint16_t* WhhB  = (uint16_t*)(ws + 42729472);      //    262,144 B
    uint16_t* WoutB = (uint16_t*)(ws + 42991616);      //     65,536 B
    float*    P     = (float*)   (ws + 43057152);      // 33,554,432 B (4 x 8 MB partials)

    k_cvt_all<<<dim3(544), 256, 0, stream>>>(Wfc, Wih_f, Wih_b, Whh_f, Whh_b, Wout,
                                             WfcB, WihB, WhhB, WoutB);
    k_fc1p <<<dim3(16, 32, 4), 512, 0, stream>>>(x, WfcB, P);
    k_fc1r <<<dim3(16, 32),    512, 0, stream>>>(P, bfc, WihB, b_f, b_b, Xp);
    k_lstm <<<dim3(32, 2),     512, 0, stream>>>(Xp, WhhB, hsB);
    k_outm <<<dim3(8, 2, 32),  256, 0, stream>>>(WoutB, hsB, bout, out);
}